// Round 1
// baseline (2184.418 us; speedup 1.0000x reference)
//
#include <hip/hip_runtime.h>

#define B_ 2
#define L_ 3584
#define E_ 820
#define H_ 20
#define D_ 41
#define CB_ 7
#define LC_ 512      // L_/CB_
#define TOPK_ 16
#define NSEL_ 112    // TOPK_*CB_
#define QB_ 112      // L_/32 query-blocks per head
#define SCALE 0.15617376188860607f  // 1/sqrt(41)

typedef unsigned short bfu;
typedef __attribute__((ext_vector_type(8))) short bf16x8;   // 8 bf16 (4 VGPRs)
typedef __attribute__((ext_vector_type(4))) float f32x4;    // MFMA C/D

__device__ __forceinline__ float b2f(bfu h) {
    union { unsigned u; float f; } c; c.u = ((unsigned)h) << 16; return c.f;
}
__device__ __forceinline__ bfu f2b(float f) {
    union { float f; unsigned u; } c; c.f = f;
    unsigned u = c.u;
    return (bfu)((u + 0x7fffu + ((u >> 16) & 1u)) >> 16);
}
__device__ __forceinline__ void b2x2(unsigned u, float& a, float& b) {
    union { unsigned u; float f; } c0, c1;
    c0.u = u << 16; c1.u = u & 0xffff0000u;
    a = c0.f; b = c1.f;
}

// ---------------- workspace layout (bytes) — per-batch reuse ----------------
#define NHLD ((size_t)H_ * L_ * D_)
#define NHCD ((size_t)H_ * LC_ * D_)
#define OFF_R1   ((size_t)0)                         // fp32 (k32 then q32)
#define OFF_V32  (OFF_R1  + NHLD * 4)
#define OFF_K16  (OFF_V32 + NHLD * 4)                // bf16
#define OFF_KC   (OFF_K16 + NHLD * 2)                // fp32
#define OFF_VC   (OFF_KC  + NHCD * 4)                // fp32
#define OFF_BS   (OFF_VC  + NHCD * 4)                // fp64 (atomic fallback)
#define OFF_IDX  (OFF_BS  + (size_t)H_ * LC_ * 8)    // int
#define WS_NEEDED (OFF_IDX + (size_t)H_ * TOPK_ * 4)
// optional extension: per-block fp32 block-score partials [H][QB_][LC_]
#define OFF_BSP  WS_NEEDED
#define WS_BIG   (OFF_BSP + (size_t)H_ * QB_ * LC_ * 4)

// ================= K-fail =================
__global__ __launch_bounds__(256) void k_fail(float* __restrict__ out, int n) {
    int i = blockIdx.x * 256 + threadIdx.x;
    if (i < n) out[i] = 0.f;
}

// ================= K0: zero block scores (double, atomic-fallback mode only) ==
__global__ __launch_bounds__(256) void k_zero_d(double* __restrict__ p, int n) {
    int i = blockIdx.x * 256 + threadIdx.x;
    if (i < n) p[i] = 0.0;
}

// ================= K1 v3: projection, 2 cols/thread, xs in 2 E-halves (27.9 KB LDS) ===
// grid (224, 2, nz), block 256. 16 rows x 512 cols per block.
__global__ __launch_bounds__(256) void k_proj2(
    const float* __restrict__ x,
    const float* __restrict__ wA, const float* __restrict__ bA, float* __restrict__ outA,
    const float* __restrict__ wB, const float* __restrict__ bB, float* __restrict__ outB,
    int b)
{
    __shared__ float xs[410 * 17];   // 27,880 B
    const float* w    = (blockIdx.z == 0) ? wA : wB;
    const float* bias = (blockIdx.z == 0) ? bA : bB;
    float* outp       = (blockIdx.z == 0) ? outA : outB;
    const int row0 = blockIdx.x * 16;
    const int c0 = blockIdx.y * 512 + threadIdx.x;   // always < 820
    const int c1 = c0 + 256;
    const bool a1 = (c1 < E_);
    const int cc1 = a1 ? c1 : (E_ - 1);
    float acc0[16], acc1[16];
    const float bb0 = bias[c0];
    const float bb1 = bias[cc1];
#pragma unroll
    for (int r = 0; r < 16; r++) { acc0[r] = bb0; acc1[r] = bb1; }

    for (int half = 0; half < 2; half++) {
        for (int i = threadIdx.x; i < 16 * 410; i += 256) {
            int r = i / 410, e = i - r * 410;
            xs[e * 17 + r] = x[((size_t)b * L_ + row0 + r) * E_ + half * 410 + e];
        }
        __syncthreads();
        const float* wp0 = w + (size_t)half * 410 * E_ + c0;
        const float* wp1 = w + (size_t)half * 410 * E_ + cc1;
#pragma unroll 2
        for (int e = 0; e < 410; e++) {
            float w0  = wp0[(size_t)e * E_];
            float w1v = wp1[(size_t)e * E_];
            const float* xr = &xs[e * 17];
#pragma unroll
            for (int r = 0; r < 16; r++) {
                acc0[r] = fmaf(xr[r], w0,  acc0[r]);
                acc1[r] = fmaf(xr[r], w1v, acc1[r]);
            }
        }
        __syncthreads();
    }
    {
        const int h = c0 / D_, d = c0 - h * D_;
#pragma unroll
        for (int r = 0; r < 16; r++)
            outp[((size_t)h * L_ + row0 + r) * D_ + d] = acc0[r];
    }
    if (a1) {
        const int h = c1 / D_, d = c1 - h * D_;
#pragma unroll
        for (int r = 0; r < 16; r++)
            outp[((size_t)h * L_ + row0 + r) * D_ + d] = acc1[r];
    }
}

// ================= K2: compression MLP (fp32), 3-way split hidden phase ==========
// grid (H_*LC_/4), block 256 (4 waves, one row each)
__global__ __launch_bounds__(256) void k_cmlp(
    const float* __restrict__ src32,
    const float* __restrict__ w1, const float* __restrict__ b1,
    const float* __restrict__ w2, const float* __restrict__ b2,
    float* __restrict__ dstc, bfu* __restrict__ dst16)
{
    __shared__ float in_s[4][CB_ * D_];
    __shared__ float h_s[4][20];
    const int tid = threadIdx.x, lane = tid & 63, wave = tid >> 6;
    const int row = blockIdx.x * 4 + wave;            // h*LC_ + c
    const int h = row / LC_, c = row - h * LC_;
    const size_t base = ((size_t)h * L_ + c * CB_) * D_;
    for (int i = lane; i < CB_ * D_; i += 64) {
        float fv = src32[base + i];
        in_s[wave][i] = fv;
        if (dst16) dst16[base + i] = f2b(fv);
    }
    __syncthreads();
    if (lane < 60) {
        const int col = lane % 20, chunk = lane / 20;
        const int i0 = chunk * 96;
        const int i1 = (chunk == 2) ? (CB_ * D_) : (i0 + 96);
        float a = (chunk == 0) ? b1[col] : 0.f;
        for (int i = i0; i < i1; i++) a += in_s[wave][i] * w1[i * 20 + col];
        float aa = __shfl_down(a, 20);
        float ab = __shfl_down(a, 40);
        if (lane < 20) h_s[wave][lane] = fmaxf(a + aa + ab, 0.f);
    }
    __syncthreads();
    if (lane < D_) {
        float a = b2[lane];
#pragma unroll
        for (int j = 0; j < 20; j++) a += h_s[wave][j] * w2[j * D_ + lane];
        dstc[(size_t)row * D_ + lane] = a;
    }
}

// ================= K3 v6: compressed attention, 32 queries/block =================
// grid (20, 112), block 256. Wave owns 8 queries; lane owns keys r*64+lane (r=0..7).
// Scores fp32 (ranking-exact). Block scores: fp32 per-block partial to global (no
// atomics) when bsp != nullptr, else legacy fp64 atomics. PV: bf16 MFMA 16x16x32,
// K=512 split 128/wave, fp32 cross-wave LDS reduction.
__global__ __launch_bounds__(256) void k_comp(
    const float* __restrict__ q32, const float* __restrict__ kc,
    const float* __restrict__ vc, const float* __restrict__ wg,
    const float* __restrict__ bg, float* __restrict__ outp,
    double* __restrict__ bscore, float* __restrict__ bsp, int b)
{
    // scratch union: kcs [128][44] f32 (22,528) / bs_part [4][512] f32 (8,192)
    //              / vcT [48][264] bf16 (25,344) / red [4][32][48] f32 (24,576)
    __shared__ __align__(16) char scr[25344];
    __shared__ __align__(16) bfu p_s[32][520];        // 33,280 B (pad 520: 16B-aligned rows, bank-spread 4)
    __shared__ __align__(16) float q_s[32][44];       // 5,632 B
    __shared__ float g0_s[32];                        // total 64,384 B
    const int h = blockIdx.x;
    const int q0 = blockIdx.y * 32;
    const int tid = threadIdx.x, lane = tid & 63, wave = tid >> 6;
    const float* kcb = kc + (size_t)h * LC_ * D_;
    const float* vcb = vc + (size_t)h * LC_ * D_;
    float* kcs = (float*)scr;

    for (int i = tid; i < 32 * D_; i += 256) {
        int qq = i / D_, d = i - qq * D_;
        q_s[qq][d] = q32[((size_t)h * L_ + q0 + qq) * D_ + d];
    }
    __syncthreads();

    if (tid < 32) {   // gates (fp32)
        float a0 = bg[0], a1 = bg[1], a2 = bg[2];
        for (int d = 0; d < D_; d++) {
            float qd = q_s[tid][d];
            a0 += qd * wg[d * 3 + 0];
            a1 += qd * wg[d * 3 + 1];
            a2 += qd * wg[d * 3 + 2];
        }
        float gm = fmaxf(a0, fmaxf(a1, a2));
        float e0 = __expf(a0 - gm), e1 = __expf(a1 - gm), e2 = __expf(a2 - gm);
        g0_s[tid] = e0 / (e0 + e1 + e2);
    }

    // ---- scores (fp32 kc): 4 stages of 128 keys, single buffer ----
    float s[8][8];
#pragma unroll
    for (int r = 0; r < 8; r++)
#pragma unroll
        for (int qi = 0; qi < 8; qi++) s[r][qi] = 0.f;

    for (int st = 0; st < 4; st++) {
        for (int i = tid; i < 128 * D_; i += 256) {
            int j = i / D_, d = i - j * D_;
            kcs[j * 44 + d] = kcb[(size_t)st * 128 * D_ + i];
        }
        __syncthreads();
        const int r0 = st * 2, r1 = r0 + 1;
        for (int dc = 0; dc < 10; dc++) {
            float4 qv[8];
#pragma unroll
            for (int qi = 0; qi < 8; qi++) qv[qi] = *(const float4*)&q_s[wave * 8 + qi][dc * 4];
            float4 k0 = *(const float4*)&kcs[lane * 44 + dc * 4];
            float4 k1 = *(const float4*)&kcs[(64 + lane) * 44 + dc * 4];
#pragma unroll
            for (int qi = 0; qi < 8; qi++) {
                s[r0][qi] += qv[qi].x * k0.x + qv[qi].y * k0.y + qv[qi].z * k0.z + qv[qi].w * k0.w;
                s[r1][qi] += qv[qi].x * k1.x + qv[qi].y * k1.y + qv[qi].z * k1.z + qv[qi].w * k1.w;
            }
        }
        {   // tail d = 40
            float kt0 = kcs[lane * 44 + 40];
            float kt1 = kcs[(64 + lane) * 44 + 40];
#pragma unroll
            for (int qi = 0; qi < 8; qi++) {
                float qt = q_s[wave * 8 + qi][40];
                s[r0][qi] += qt * kt0;
                s[r1][qi] += qt * kt1;
            }
        }
        __syncthreads();   // compute done before next stage overwrites kcs
    }

    // ---- softmax (fp32, ranking-exact) ----
    float bs_acc[8];
#pragma unroll
    for (int r = 0; r < 8; r++) bs_acc[r] = 0.f;
#pragma unroll
    for (int qi = 0; qi < 8; qi++) {
        float m = -1e30f;
#pragma unroll
        for (int r = 0; r < 8; r++) { s[r][qi] *= SCALE; m = fmaxf(m, s[r][qi]); }
        for (int o = 32; o; o >>= 1) m = fmaxf(m, __shfl_xor(m, o));
        float e[8], lsum = 0.f;
#pragma unroll
        for (int r = 0; r < 8; r++) { e[r] = expf(s[r][qi] - m); lsum += e[r]; }
        for (int o = 32; o; o >>= 1) lsum += __shfl_xor(lsum, o);
        float inv = 1.f / lsum;
#pragma unroll
        for (int r = 0; r < 8; r++) {
            float p = e[r] * inv;
            p_s[wave * 8 + qi][r * 64 + lane] = f2b(p);
            bs_acc[r] += p;
        }
    }

    // ---- block scores: per-wave partials in scratch -> fp32 global partial
    //      (or legacy fp64 atomics when bsp == nullptr) ----
    float* bs_part = (float*)scr;      // [4][512]
#pragma unroll
    for (int r = 0; r < 8; r++) bs_part[wave * LC_ + r * 64 + lane] = bs_acc[r];
    __syncthreads();
    for (int j = tid; j < LC_; j += 256) {
        float v = bs_part[j] + bs_part[LC_ + j] + bs_part[2 * LC_ + j] + bs_part[3 * LC_ + j];
        if (bsp) bsp[((size_t)h * QB_ + blockIdx.y) * LC_ + j] = v;
        else     atomicAdd(&bscore[h * LC_ + j], (double)v);
    }
    __syncthreads();                   // bs_part dead

    // ---- PV via MFMA: P[32x512] bf16 x Vc[512x48] bf16 (d>=41 zero) ----
    // A frag: lane holds P[mt*16 + (lane&15)][k0 + (lane>>4)*8 + i], i=0..7
    // B frag: lane holds Vc[k0 + (lane>>4)*8 + i][nt*16 + (lane&15)]  (vcT row-major [n][k])
    // D: lane reg r -> (q = mt*16 + (lane>>4)*4 + r, d = nt*16 + (lane&15))
    bfu* vcT = (bfu*)scr;              // [48][264] bf16 per K-half (row stride 528 B, 16B-aligned)
    const int lrow = lane & 15, lgr = lane >> 4;
    f32x4 acc[2][3];
#pragma unroll
    for (int mt = 0; mt < 2; mt++)
#pragma unroll
        for (int nt = 0; nt < 3; nt++)
            acc[mt][nt] = (f32x4){0.f, 0.f, 0.f, 0.f};

    for (int half = 0; half < 2; half++) {
        for (int i = tid; i < 48 * 256; i += 256) {
            int n = i % 48, j = i / 48;   // n fast -> coalesced global reads
            vcT[n * 264 + j] = (n < D_) ? f2b(vcb[(size_t)(half * 256 + j) * D_ + n]) : (bfu)0;
        }
        __syncthreads();
#pragma unroll
        for (int ks = 0; ks < 2; ks++) {
            const int kl = wave * 64 + ks * 32 + lgr * 8;   // local k in this half
            const int kg = half * 256 + kl;                 // global k (p_s column)
            bf16x8 a0 = *(const bf16x8*)&p_s[lrow][kg];
            bf16x8 a1 = *(const bf16x8*)&p_s[16 + lrow][kg];
#pragma unroll
            for (int nt = 0; nt < 3; nt++) {
                bf16x8 bv = *(const bf16x8*)&vcT[(nt * 16 + lrow) * 264 + kl];
                acc[0][nt] = __builtin_amdgcn_mfma_f32_16x16x32_bf16(a0, bv, acc[0][nt], 0, 0, 0);
                acc[1][nt] = __builtin_amdgcn_mfma_f32_16x16x32_bf16(a1, bv, acc[1][nt], 0, 0, 0);
            }
        }
        __syncthreads();   // MFMA reads done before next half restages / red reuse
    }

    // ---- cross-wave K-reduction + gated output ----
    float* red = (float*)scr;          // [4][32][48]
#pragma unroll
    for (int mt = 0; mt < 2; mt++)
#pragma unroll
        for (int nt = 0; nt < 3; nt++)
#pragma unroll
            for (int r = 0; r < 4; r++)
                red[(wave * 32 + mt * 16 + lgr * 4 + r) * 48 + nt * 16 + lrow] = acc[mt][nt][r];
    __syncthreads();
    for (int i = tid; i < 32 * 48; i += 256) {
        int q = i / 48, d = i - q * 48;
        if (d < D_) {
            float v = red[i] + red[1536 + i] + red[2 * 1536 + i] + red[3 * 1536 + i];
            outp[((size_t)(b * L_ + q0 + q)) * (H_ * D_) + h * D_ + d] = g0_s[q] * v;
        }
    }
}

// ================= K4: top-k (per batch; fp32 partial reduce in fp64, or legacy fp64) ==
// grid 20, block 64
__global__ __launch_bounds__(64) void k_topk(const double* __restrict__ bs,
                                             const float* __restrict__ bsp,
                                             int* __restrict__ idxo)
{
    __shared__ double vb_[64];
    __shared__ int ib_[64];
    __shared__ int win;
    const int h = blockIdx.x, lane = threadIdx.x;
    double vals[8];
    if (bsp) {   // deterministic sequential fp64 sum of the 112 fp32 per-block partials
#pragma unroll
        for (int r = 0; r < 8; r++) vals[r] = 0.0;
        for (int pb = 0; pb < QB_; pb++) {
            const float* rowp = &bsp[((size_t)h * QB_ + pb) * LC_];
#pragma unroll
            for (int r = 0; r < 8; r++) vals[r] += (double)rowp[r * 64 + lane];
        }
    } else {
#pragma unroll
        for (int r = 0; r < 8; r++) vals[r] = bs[h * LC_ + r * 64 + lane];
    }
    for (int t = 0; t < TOPK_; t++) {
        double bv = -1e30; int bi = 0x7fffffff;
#pragma unroll
        for (int r = 0; r < 8; r++) {
            int j = r * 64 + lane;
            bool better = (vals[r] > bv) || (vals[r] == bv && j < bi);
            if (better) { bv = vals[r]; bi = j; }
        }
        vb_[lane] = bv; ib_[lane] = bi;
        __syncthreads();
        if (lane == 0) {
            double best = -1e30; int besti = 0x7fffffff;
            for (int u = 0; u < 64; u++) {
                if (vb_[u] > best || (vb_[u] == best && ib_[u] < besti)) { best = vb_[u]; besti = ib_[u]; }
            }
            idxo[h * TOPK_ + t] = besti;
            win = besti;
        }
        __syncthreads();
        int w = win;
#pragma unroll
        for (int r = 0; r < 8; r++)
            if ((w >> 6) == r && (w & 63) == lane) vals[r] = -1e30;
        __syncthreads();
    }
}

// ================= K5 v3: selected + window attention, 32 queries/block ==============
// grid (20, 112), block 256. Wave owns 8 queries in 2 groups of 4.
__global__ __launch_bounds__(256) void k_selwin(
    const float* __restrict__ q32, const bfu* __restrict__ k16,
    const float* __restrict__ v32, const int* __restrict__ idxp,
    const float* __restrict__ wg, const float* __restrict__ bg,
    float* __restrict__ outp, int b)
{
    __shared__ __align__(16) bfu ks_s[119][44];      // 112 sel + 7 window keys
    __shared__ __align__(16) float vsT[D_][130];     // fp32 v^T, pad 130
    __shared__ __align__(16) float q_s[32][44];
    __shared__ __align__(16) bfu p_s[32][NSEL_];
    __shared__ int rows_s[NSEL_];
    __shared__ float g1_s[32];
    __shared__ float pw_s[32][CB_];                  // g2-scaled window probs
    const int h = blockIdx.x;
    const int q0 = blockIdx.y * 32;
    const int tid = threadIdx.x, lane = tid & 63, wave = tid >> 6;
    const size_t kvbase = (size_t)h * L_ * D_;

    for (int i = tid; i < 32 * D_; i += 256) {
        int qq = i / D_, d = i - qq * D_;
        q_s[qq][d] = q32[((size_t)h * L_ + q0 + qq) * D_ + d];
    }
    if (tid < NSEL_) {
        int t = tid / CB_;
        rows_s[tid] = idxp[h * TOPK_ + t] * CB_ + (tid - t * CB_);
    }
    __syncthreads();

    for (int i = tid; i < 119 * D_; i += 256) {
        int key = i / D_, d = i - key * D_;
        int row = (key < NSEL_) ? rows_s[key] : (L_ - CB_ + (key - NSEL_));
        ks_s[key][d] = k16[kvbase + (size_t)row * D_ + d];
        vsT[d][key]  = v32[kvbase + (size_t)row * D_ + d];
    }
    __syncthreads();

    if (tid < 32) {   // gates + window softmax (x g2)
        float a0 = bg[0], a1 = bg[1], a2 = bg[2];
        for (int d = 0; d < D_; d++) {
            float qd = q_s[tid][d];
            a0 += qd * wg[d * 3 + 0];
            a1 += qd * wg[d * 3 + 1];
            a2 += qd * wg[d * 3 + 2];
        }
        float gm = fmaxf(a0, fmaxf(a1, a2));
        float e0 = __expf(a0 - gm), e1 = __expf(a1 - gm), e2 = __expf(a2 - gm);
        float ginv = 1.f / (e0 + e1 + e2);
        g1_s[tid] = e1 * ginv;
        float g2 = e2 * ginv;
        float sw[CB_];
        float m = -1e30f;
        for (int i = 0; i < CB_; i++) {
            float ss = 0.f;
            for (int d = 0; d < D_; d++) ss += q_s[tid][d] * b2f(ks_s[NSEL_ + i][d]);
            sw[i] = ss * SCALE;
            m = fmaxf(m, sw[i]);
        }
        float lsum = 0.f;
        for (int i = 0; i < CB_; i++) { sw[i] = __expf(sw[i] - m); lsum += sw[i]; }
        float winv = g2 / lsum;
        for (int i = 0; i < CB_; i++) pw_s[tid][i] = sw[i] * winv;
    }
    __syncthreads();

    const bool v1 = (64 + lane) < NSEL_;
    const int row1c = v1 ? (64 + lane) : 0;
    for (int g = 0; g < 2; g++) {
        const int qb = wave * 8 + g * 4;
        float s0[4] = {0, 0, 0, 0}, s1[4] = {0, 0, 0, 0};
        for (int dc = 0; dc < 10; dc++) {
            float4 qv[4];
#pragma unroll
            for (int qi = 0; qi < 4; qi++) qv[qi] = *(const float4*)&q_s[qb + qi][dc * 4];
            uint2 ra = *(const uint2*)&ks_s[lane][dc * 4];
            uint2 rb = *(const uint2*)&ks_s[row1c][dc * 4];
            float a0, a1, a2, a3, c0, c1, c2, c3;
            b2x2(ra.x, a0, a1); b2x2(ra.y, a2, a3);
            b2x2(rb.x, c0, c1); b2x2(rb.y, c2, c3);
#pragma unroll
            for (int qi = 0; qi < 4; qi++) {
                s0[qi] += qv[qi].x * a0 + qv[qi].y * a1 + qv[qi].z * a2 + qv[qi].w * a3;
                s1[qi] += qv[qi].x * c0 + qv[qi].y * c1 + qv[qi].z * c2 + qv[qi].w * c3;
            }
        }
        {
            float ka = b2f(ks_s[lane][40]);
            float kb = b2f(ks_s[row1c][40]);
#pragma unroll
            for (int qi = 0; qi < 4; qi++) {
                float qt = q_s[qb + qi][40];
                s0[qi] += qt * ka; s1[qi] += qt * kb;
            }
        }
#pragma unroll
        for (int qi = 0; qi < 4; qi++) {
            float a0 = s0[qi] * SCALE;
            float a1 = v1 ? s1[qi] * SCALE : -1e30f;
            float m = fmaxf(a0, a1);
            for (int o = 32; o; o >>= 1) m = fmaxf(m, __shfl_xor(m, o));
            float e0 = __expf(a0 - m);
            float e1 = v1 ? __expf(a1 - m) : 0.f;
            float lsum = e0 + e1;
            for (int o = 32; o; o >>= 1) lsum += __shfl_xor(lsum, o);
            float inv = 1.f / lsum;
            p_s[qb + qi][lane] = f2b(e0 * inv);
            if (v1) p_s[qb + qi][64 + lane] = f2b(e1 * inv);
        }
    }
    __syncthreads();

    if (lane < D_) {
        for (int g = 0; g < 2; g++) {
            const int qb = wave * 8 + g * 4;
            float acc[4] = {0, 0, 0, 0};
            for (int jc = 0; jc < NSEL_; jc += 4) {
                float2 va = *(const float2*)&vsT[lane][jc];
                float2 vb = *(const float2*)&vsT[lane][jc + 2];
#pragma unroll
                for (int qi = 0; qi < 4; qi++) {
                    uint2 pp = *(const uint2*)&p_s[qb + qi][jc];
                    float p0, p1, p2, p3;
                    b2x2(pp.x, p0, p1); b2x2(pp.y, p2, p3);
                    acc[qi] += p0 * va.x + p1 * va.y + p2 * vb.x + p3 * vb.y;
                }
            }
#pragma unroll
            for (int qi = 0; qi < 4; qi++) {
                int row = qb + qi;
                float wvv = 0.f;
#pragma unroll
                for (int i = 0; i < CB_; i++) wvv += pw_s[row][i] * vsT[lane][NSEL_ + i];
                float* op = &outp[((size_t)(b * L_ + q0 + row)) * (H_ * D_) + h * D_ + lane];
                *op = *op + g1_s[row] * acc[qi] + wvv;
            }
        }
    }
}

extern "C" void kernel_launch(void* const* d_in, const int* in_sizes, int n_in,
                              void* d_out, int out_size, void* d_ws, size_t ws_size,
                              hipStream_t stream) {
    (void)in_sizes; (void)n_in;
    const float* x  = (const float*)d_in[0];
    const float* wq = (const float*)d_in[1];  const float* bq = (const float*)d_in[2];
    const float* wk = (const float*)d_in[3];  const float* bk = (const float*)d_in[4];
    const float* wv = (const float*)d_in[5];  const float* bv = (const float*)d_in[6];
    const float* w1 = (const float*)d_in[7];  const float* b1 = (const float*)d_in[8];
    const float* w2 = (const float*)d_in[9];  const float* b2 = (const float*)d_in[10];
    const float* wg = (const float*)d_in[11]; const float* bg = (const float*)d_in[12];

    if (d_ws == nullptr || ws_size < WS_NEEDED) {
        k_fail<<<dim3((out_size + 255) / 256), 256, 0, stream>>>((float*)d_out, out_size);
        return;
    }

    char* ws = (char*)d_ws;
    float*  r1   = (float*)(ws + OFF_R1);    // k32 then q32
    float*  v32  = (float*)(ws + OFF_V32);
    bfu*    k16  = (bfu*)(ws + OFF_K16);
    float*  kc   = (float*)(ws + OFF_KC);
    float*  vc   = (float*)(ws + OFF_VC);
    double* bsc  = (double*)(ws + OFF_BS);
    int*    idxp = (int*)(ws + OFF_IDX);
    float*  outp = (float*)d_out;
    // atomic-free block-score partials if workspace allows (else legacy fp64 atomics)
    const bool big = (ws_size >= WS_BIG);
    float*  bsp  = big ? (float*)(ws + OFF_BSP) : (float*)nullptr;

    for (int b = 0; b < B_; b++) {
        if (!big)
            k_zero_d<<<dim3((H_ * LC_ + 255) / 256), 256, 0, stream>>>(bsc, H_ * LC_);
        // K -> r1 and V -> v32 in one fused launch
        k_proj2<<<dim3(L_ / 16, 2, 2), 256, 0, stream>>>(x, wk, bk, r1, wv, bv, v32, b);
        k_cmlp<<<dim3(H_ * LC_ / 4), 256, 0, stream>>>(r1, w1, b1, w2, b2, kc, k16);
        // Q -> r1 (overwrites k32; cmlpK done)
        k_proj2<<<dim3(L_ / 16, 2, 1), 256, 0, stream>>>(x, wq, bq, r1, wq, bq, r1, b);
        k_cmlp<<<dim3(H_ * LC_ / 4), 256, 0, stream>>>(v32, w1, b1, w2, b2, vc, (bfu*)nullptr);
        k_comp<<<dim3(H_, QB_), 256, 0, stream>>>(r1, kc, vc, wg, bg, outp, bsc, bsp, b);
        k_topk<<<dim3(H_), 64, 0, stream>>>(bsc, bsp, idxp);
        k_selwin<<<dim3(H_, L_ / 32), 256, 0, stream>>>(r1, k16, v32, idxp, wg, bg, outp, b);
    }
}

// Round 2
// 2137.616 us; speedup vs baseline: 1.0219x; 1.0219x over previous
//
#include <hip/hip_runtime.h>

#define B_ 2
#define L_ 3584
#define E_ 820
#define H_ 20
#define D_ 41
#define CB_ 7
#define LC_ 512      // L_/CB_
#define TOPK_ 16
#define NSEL_ 112    // TOPK_*CB_
#define QB_ 112      // L_/32 query-blocks per head
#define NREP_ 4      // fp64 score replicas (fallback path)
#define SCALE 0.15617376188860607f  // 1/sqrt(41)

typedef unsigned short bfu;
typedef __attribute__((ext_vector_type(8))) short bf16x8;   // 8 bf16 (4 VGPRs)
typedef __attribute__((ext_vector_type(4))) float f32x4;    // MFMA C/D

__device__ __forceinline__ float b2f(bfu h) {
    union { unsigned u; float f; } c; c.u = ((unsigned)h) << 16; return c.f;
}
__device__ __forceinline__ bfu f2b(float f) {
    union { float f; unsigned u; } c; c.f = f;
    unsigned u = c.u;
    return (bfu)((u + 0x7fffu + ((u >> 16) & 1u)) >> 16);
}
__device__ __forceinline__ void b2x2(unsigned u, float& a, float& b) {
    union { unsigned u; float f; } c0, c1;
    c0.u = u << 16; c1.u = u & 0xffff0000u;
    a = c0.f; b = c1.f;
}

// ---------------- workspace layout (bytes) — per-batch reuse ----------------
#define NHLD ((size_t)H_ * L_ * D_)
#define NHCD ((size_t)H_ * LC_ * D_)
#define OFF_R1   ((size_t)0)                         // fp32 (k32 then q32)
#define OFF_V32  (OFF_R1  + NHLD * 4)
#define OFF_K16  (OFF_V32 + NHLD * 4)                // bf16
#define OFF_KC   (OFF_K16 + NHLD * 2)                // fp32 (ranking-exact)
#define OFF_VC16 (OFF_KC  + NHCD * 4)                // bf16 (PV operand precision)
#define OFF_BS   (OFF_VC16 + NHCD * 2)               // fp64 x NREP_ (atomic fallback)
#define OFF_IDX  (OFF_BS  + (size_t)NREP_ * H_ * LC_ * 8)  // int
#define WS_NEEDED (OFF_IDX + (size_t)H_ * TOPK_ * 4)       // 32,236,800 < old 32,830,720
// optional extension: per-block fp32 block-score partials [H][QB_][LC_]
#define OFF_BSP  WS_NEEDED
#define WS_BIG   (OFF_BSP + (size_t)H_ * QB_ * LC_ * 4)    // 36,824,320 < old 37,418,240

// ================= K-fail =================
__global__ __launch_bounds__(256) void k_fail(float* __restrict__ out, int n) {
    int i = blockIdx.x * 256 + threadIdx.x;
    if (i < n) out[i] = 0.f;
}

// ================= K0: zero block scores (double, atomic-fallback mode only) ==
__global__ __launch_bounds__(256) void k_zero_d(double* __restrict__ p, int n) {
    int i = blockIdx.x * 256 + threadIdx.x;
    if (i < n) p[i] = 0.0;
}

// ================= K1 v3: projection, 2 cols/thread, xs in 2 E-halves (27.9 KB LDS) ===
// grid (224, 2, nz), block 256. 16 rows x 512 cols per block.
__global__ __launch_bounds__(256) void k_proj2(
    const float* __restrict__ x,
    const float* __restrict__ wA, const float* __restrict__ bA, float* __restrict__ outA,
    const float* __restrict__ wB, const float* __restrict__ bB, float* __restrict__ outB,
    int b)
{
    __shared__ float xs[410 * 17];   // 27,880 B
    const float* w    = (blockIdx.z == 0) ? wA : wB;
    const float* bias = (blockIdx.z == 0) ? bA : bB;
    float* outp       = (blockIdx.z == 0) ? outA : outB;
    const int row0 = blockIdx.x * 16;
    const int c0 = blockIdx.y * 512 + threadIdx.x;   // always < 820
    const int c1 = c0 + 256;
    const bool a1 = (c1 < E_);
    const int cc1 = a1 ? c1 : (E_ - 1);
    float acc0[16], acc1[16];
    const float bb0 = bias[c0];
    const float bb1 = bias[cc1];
#pragma unroll
    for (int r = 0; r < 16; r++) { acc0[r] = bb0; acc1[r] = bb1; }

    for (int half = 0; half < 2; half++) {
        for (int i = threadIdx.x; i < 16 * 410; i += 256) {
            int r = i / 410, e = i - r * 410;
            xs[e * 17 + r] = x[((size_t)b * L_ + row0 + r) * E_ + half * 410 + e];
        }
        __syncthreads();
        const float* wp0 = w + (size_t)half * 410 * E_ + c0;
        const float* wp1 = w + (size_t)half * 410 * E_ + cc1;
#pragma unroll 2
        for (int e = 0; e < 410; e++) {
            float w0  = wp0[(size_t)e * E_];
            float w1v = wp1[(size_t)e * E_];
            const float* xr = &xs[e * 17];
#pragma unroll
            for (int r = 0; r < 16; r++) {
                acc0[r] = fmaf(xr[r], w0,  acc0[r]);
                acc1[r] = fmaf(xr[r], w1v, acc1[r]);
            }
        }
        __syncthreads();
    }
    {
        const int h = c0 / D_, d = c0 - h * D_;
#pragma unroll
        for (int r = 0; r < 16; r++)
            outp[((size_t)h * L_ + row0 + r) * D_ + d] = acc0[r];
    }
    if (a1) {
        const int h = c1 / D_, d = c1 - h * D_;
#pragma unroll
        for (int r = 0; r < 16; r++)
            outp[((size_t)h * L_ + row0 + r) * D_ + d] = acc1[r];
    }
}

// ================= K2: compression MLP (fp32), 3-way split hidden phase ==========
// grid (H_*LC_/4), block 256 (4 waves, one row each)
// dstc16 != null -> write result as bf16 (V-compression path); else fp32 to dstc.
__global__ __launch_bounds__(256) void k_cmlp(
    const float* __restrict__ src32,
    const float* __restrict__ w1, const float* __restrict__ b1,
    const float* __restrict__ w2, const float* __restrict__ b2,
    float* __restrict__ dstc, bfu* __restrict__ dst16, bfu* __restrict__ dstc16)
{
    __shared__ float in_s[4][CB_ * D_];
    __shared__ float h_s[4][20];
    const int tid = threadIdx.x, lane = tid & 63, wave = tid >> 6;
    const int row = blockIdx.x * 4 + wave;            // h*LC_ + c
    const int h = row / LC_, c = row - h * LC_;
    const size_t base = ((size_t)h * L_ + c * CB_) * D_;
    for (int i = lane; i < CB_ * D_; i += 64) {
        float fv = src32[base + i];
        in_s[wave][i] = fv;
        if (dst16) dst16[base + i] = f2b(fv);
    }
    __syncthreads();
    if (lane < 60) {
        const int col = lane % 20, chunk = lane / 20;
        const int i0 = chunk * 96;
        const int i1 = (chunk == 2) ? (CB_ * D_) : (i0 + 96);
        float a = (chunk == 0) ? b1[col] : 0.f;
        for (int i = i0; i < i1; i++) a += in_s[wave][i] * w1[i * 20 + col];
        float aa = __shfl_down(a, 20);
        float ab = __shfl_down(a, 40);
        if (lane < 20) h_s[wave][lane] = fmaxf(a + aa + ab, 0.f);
    }
    __syncthreads();
    if (lane < D_) {
        float a = b2[lane];
#pragma unroll
        for (int j = 0; j < 20; j++) a += h_s[wave][j] * w2[j * D_ + lane];
        if (dstc16) dstc16[(size_t)row * D_ + lane] = f2b(a);
        else        dstc [(size_t)row * D_ + lane] = a;
    }
}

// ================= K3 v7: compressed attention, 32 queries/block =================
// grid (QB_, H_) [qb fast -> same-head blocks adjacent -> per-XCD L2 panel reuse].
// LDS 48.0 KB -> 3 blocks/CU (12 waves). Scores fp32 in regs (ranking-exact).
// P written/consumed in 2 K-halves (p_s halved). PV: bf16 MFMA, Vc already bf16.
// Block scores kept in regs until the end; fp32 partial store (bsp) or 4-replica
// fp64 atomics (fallback) fired at kernel end (ack latency overlaps nothing).
__global__ __launch_bounds__(256, 3) void k_comp(
    const float* __restrict__ q32, const float* __restrict__ kc,
    const bfu* __restrict__ vc16, const float* __restrict__ wg,
    const float* __restrict__ bg, float* __restrict__ outp,
    double* __restrict__ bscore, float* __restrict__ bsp, int b)
{
    // scratch union: kcs [128][44] f32 (22,528) / vcT [48][264] bf16 (25,344)
    //              / red [4][1536] f32 (24,576) / bs_part [4][512] f32 (8,192)
    __shared__ __align__(16) char scr[25344];
    __shared__ __align__(16) bfu p_s[32][264];        // 16,896 B (one K-half of P)
    __shared__ __align__(16) float q_s[32][44];       // 5,632 B
    __shared__ float g0_s[32];                        // total 48,000 B
    const int qb = blockIdx.x, h = blockIdx.y;
    const int q0 = qb * 32;
    const int tid = threadIdx.x, lane = tid & 63, wave = tid >> 6;
    const float* kcb = kc   + (size_t)h * LC_ * D_;
    const bfu*   vcb = vc16 + (size_t)h * LC_ * D_;
    float* kcs = (float*)scr;

    for (int i = tid; i < 32 * D_; i += 256) {
        int qq = i / D_, d = i - qq * D_;
        q_s[qq][d] = q32[((size_t)h * L_ + q0 + qq) * D_ + d];
    }
    __syncthreads();

    if (tid < 32) {   // gates (fp32)
        float a0 = bg[0], a1 = bg[1], a2 = bg[2];
        for (int d = 0; d < D_; d++) {
            float qd = q_s[tid][d];
            a0 += qd * wg[d * 3 + 0];
            a1 += qd * wg[d * 3 + 1];
            a2 += qd * wg[d * 3 + 2];
        }
        float gm = fmaxf(a0, fmaxf(a1, a2));
        float e0 = __expf(a0 - gm), e1 = __expf(a1 - gm), e2 = __expf(a2 - gm);
        g0_s[tid] = e0 / (e0 + e1 + e2);
    }

    // ---- scores (fp32 kc): 4 stages of 128 keys, single buffer ----
    float s[8][8];
#pragma unroll
    for (int r = 0; r < 8; r++)
#pragma unroll
        for (int qi = 0; qi < 8; qi++) s[r][qi] = 0.f;

    for (int st = 0; st < 4; st++) {
        for (int i = tid; i < 128 * D_; i += 256) {
            int j = i / D_, d = i - j * D_;
            kcs[j * 44 + d] = kcb[(size_t)st * 128 * D_ + i];
        }
        __syncthreads();
        const int r0 = st * 2, r1 = r0 + 1;
        for (int dc = 0; dc < 10; dc++) {
            float4 qv[8];
#pragma unroll
            for (int qi = 0; qi < 8; qi++) qv[qi] = *(const float4*)&q_s[wave * 8 + qi][dc * 4];
            float4 k0 = *(const float4*)&kcs[lane * 44 + dc * 4];
            float4 k1 = *(const float4*)&kcs[(64 + lane) * 44 + dc * 4];
#pragma unroll
            for (int qi = 0; qi < 8; qi++) {
                s[r0][qi] += qv[qi].x * k0.x + qv[qi].y * k0.y + qv[qi].z * k0.z + qv[qi].w * k0.w;
                s[r1][qi] += qv[qi].x * k1.x + qv[qi].y * k1.y + qv[qi].z * k1.z + qv[qi].w * k1.w;
            }
        }
        {   // tail d = 40
            float kt0 = kcs[lane * 44 + 40];
            float kt1 = kcs[(64 + lane) * 44 + 40];
#pragma unroll
            for (int qi = 0; qi < 8; qi++) {
                float qt = q_s[wave * 8 + qi][40];
                s[r0][qi] += qt * kt0;
                s[r1][qi] += qt * kt1;
            }
        }
        __syncthreads();   // compute done before next stage overwrites kcs
    }

    // ---- softmax (fp32, ranking-exact): exp in place, keep inv per q-row ----
    float inv[8], bs_acc[8];
#pragma unroll
    for (int r = 0; r < 8; r++) bs_acc[r] = 0.f;
#pragma unroll
    for (int qi = 0; qi < 8; qi++) {
        float m = -1e30f;
#pragma unroll
        for (int r = 0; r < 8; r++) { s[r][qi] *= SCALE; m = fmaxf(m, s[r][qi]); }
        for (int o = 32; o; o >>= 1) m = fmaxf(m, __shfl_xor(m, o));
        float lsum = 0.f;
#pragma unroll
        for (int r = 0; r < 8; r++) { s[r][qi] = expf(s[r][qi] - m); lsum += s[r][qi]; }
        for (int o = 32; o; o >>= 1) lsum += __shfl_xor(lsum, o);
        inv[qi] = 1.f / lsum;
#pragma unroll
        for (int r = 0; r < 8; r++) bs_acc[r] += s[r][qi] * inv[qi];
    }

    // ---- PV via MFMA in 2 K-halves: P[32x256] bf16 x Vc[256x48] bf16 ----
    // A frag: lane holds P[mt*16 + (lane&15)][kl + (lane>>4)*8 + i], i=0..7
    // B frag: lane holds Vc[half*256 + kl + (lane>>4)*8 + i][nt*16 + (lane&15)]
    // D: lane reg r -> (q = mt*16 + (lane>>4)*4 + r, d = nt*16 + (lane&15))
    bfu* vcT = (bfu*)scr;              // [48][264] bf16 per K-half
    const int lrow = lane & 15, lgr = lane >> 4;
    f32x4 acc[2][3];
#pragma unroll
    for (int mt = 0; mt < 2; mt++)
#pragma unroll
        for (int nt = 0; nt < 3; nt++)
            acc[mt][nt] = (f32x4){0.f, 0.f, 0.f, 0.f};

    for (int half = 0; half < 2; half++) {
        // write this half's P (keys half*256 .. half*256+255 -> cols r4*64+lane)
#pragma unroll
        for (int qi = 0; qi < 8; qi++)
#pragma unroll
            for (int r4 = 0; r4 < 4; r4++)
                p_s[wave * 8 + qi][r4 * 64 + lane] = f2b(s[half * 4 + r4][qi] * inv[qi]);
        // stage Vc^T for this half (already bf16; rows >= 41 zero)
        for (int i = tid; i < 48 * 256; i += 256) {
            int n = i / 256;           // 0..47 (exact: 48*256/256 iters, n = chunk)
            int j = i - n * 256;
            // n-slow layout would scatter global reads; use n-fast instead:
            (void)n; (void)j;
        }
        for (int i = tid; i < 48 * 256; i += 256) {
            int j = i / 48, n = i - j * 48;
            vcT[n * 264 + j] = (n < D_) ? vcb[(size_t)(half * 256 + j) * D_ + n] : (bfu)0;
        }
        __syncthreads();
        const int klb = wave * 64;
        bf16x8 a0[2], a1[2];
#pragma unroll
        for (int ks = 0; ks < 2; ks++) {
            const int kl = klb + ks * 32 + lgr * 8;
            a0[ks] = *(const bf16x8*)&p_s[lrow][kl];
            a1[ks] = *(const bf16x8*)&p_s[16 + lrow][kl];
        }
#pragma unroll
        for (int ks = 0; ks < 2; ks++) {
            const int kl = klb + ks * 32 + lgr * 8;
#pragma unroll
            for (int nt = 0; nt < 3; nt++) {
                bf16x8 bv = *(const bf16x8*)&vcT[(nt * 16 + lrow) * 264 + kl];
                acc[0][nt] = __builtin_amdgcn_mfma_f32_16x16x32_bf16(a0[ks], bv, acc[0][nt], 0, 0, 0);
                acc[1][nt] = __builtin_amdgcn_mfma_f32_16x16x32_bf16(a1[ks], bv, acc[1][nt], 0, 0, 0);
            }
        }
        __syncthreads();   // MFMA + p_s reads done before next half restages
    }

    // ---- cross-wave K-reduction (linear frag layout: conflict-free writes) ----
    float* red = (float*)scr;          // [4][1536]
#pragma unroll
    for (int mt = 0; mt < 2; mt++)
#pragma unroll
        for (int nt = 0; nt < 3; nt++)
#pragma unroll
            for (int r = 0; r < 4; r++)
                red[wave * 1536 + ((mt * 3 + nt) * 4 + r) * 64 + lane] = acc[mt][nt][r];
    __syncthreads();
    for (int i = tid; i < 32 * 48; i += 256) {
        int q = i / 48, d = i - q * 48;
        if (d < D_) {
            int mt = q >> 4, lg = (q >> 2) & 3, r = q & 3;
            int nt = d >> 4, lr = d & 15;
            int fi = ((mt * 3 + nt) * 4 + r) * 64 + lg * 16 + lr;
            float v = red[fi] + red[1536 + fi] + red[3072 + fi] + red[4608 + fi];
            outp[((size_t)(b * L_ + q0 + q)) * (H_ * D_) + h * D_ + d] = g0_s[q] * v;
        }
    }
    __syncthreads();                   // red dead

    // ---- block scores at the very end (no post-store barrier in-kernel) ----
    float* bs_part = (float*)scr;      // [4][512]
#pragma unroll
    for (int r = 0; r < 8; r++) bs_part[wave * LC_ + r * 64 + lane] = bs_acc[r];
    __syncthreads();
    for (int j = tid; j < LC_; j += 256) {
        float v = bs_part[j] + bs_part[LC_ + j] + bs_part[2 * LC_ + j] + bs_part[3 * LC_ + j];
        if (bsp) bsp[((size_t)h * QB_ + qb) * LC_ + j] = v;
        else     atomicAdd(&bscore[((size_t)(qb & (NREP_ - 1)) * H_ + h) * LC_ + j], (double)v);
    }
}

// ================= K4: top-k (per batch; fp32 partials or replicated fp64) ==
// grid 20, block 64
__global__ __launch_bounds__(64) void k_topk(const double* __restrict__ bs,
                                             const float* __restrict__ bsp,
                                             int* __restrict__ idxo)
{
    __shared__ double vb_[64];
    __shared__ int ib_[64];
    __shared__ int win;
    const int h = blockIdx.x, lane = threadIdx.x;
    double vals[8];
    if (bsp) {   // deterministic sequential fp64 sum of the 112 fp32 per-block partials
#pragma unroll
        for (int r = 0; r < 8; r++) vals[r] = 0.0;
        for (int pb = 0; pb < QB_; pb++) {
            const float* rowp = &bsp[((size_t)h * QB_ + pb) * LC_];
#pragma unroll
            for (int r = 0; r < 8; r++) vals[r] += (double)rowp[r * 64 + lane];
        }
    } else {     // sum the NREP_ fp64 replicas
#pragma unroll
        for (int r = 0; r < 8; r++) {
            int j = r * 64 + lane;
            double v = 0.0;
#pragma unroll
            for (int rep = 0; rep < NREP_; rep++)
                v += bs[((size_t)rep * H_ + h) * LC_ + j];
            vals[r] = v;
        }
    }
    for (int t = 0; t < TOPK_; t++) {
        double bv = -1e30; int bi = 0x7fffffff;
#pragma unroll
        for (int r = 0; r < 8; r++) {
            int j = r * 64 + lane;
            bool better = (vals[r] > bv) || (vals[r] == bv && j < bi);
            if (better) { bv = vals[r]; bi = j; }
        }
        vb_[lane] = bv; ib_[lane] = bi;
        __syncthreads();
        if (lane == 0) {
            double best = -1e30; int besti = 0x7fffffff;
            for (int u = 0; u < 64; u++) {
                if (vb_[u] > best || (vb_[u] == best && ib_[u] < besti)) { best = vb_[u]; besti = ib_[u]; }
            }
            idxo[h * TOPK_ + t] = besti;
            win = besti;
        }
        __syncthreads();
        int w = win;
#pragma unroll
        for (int r = 0; r < 8; r++)
            if ((w >> 6) == r && (w & 63) == lane) vals[r] = -1e30;
        __syncthreads();
    }
}

// ================= K5 v3: selected + window attention, 32 queries/block ==============
// grid (QB_, 20), block 256. Wave owns 8 queries in 2 groups of 4.
__global__ __launch_bounds__(256) void k_selwin(
    const float* __restrict__ q32, const bfu* __restrict__ k16,
    const float* __restrict__ v32, const int* __restrict__ idxp,
    const float* __restrict__ wg, const float* __restrict__ bg,
    float* __restrict__ outp, int b)
{
    __shared__ __align__(16) bfu ks_s[119][44];      // 112 sel + 7 window keys
    __shared__ __align__(16) float vsT[D_][130];     // fp32 v^T, pad 130
    __shared__ __align__(16) float q_s[32][44];
    __shared__ __align__(16) bfu p_s[32][NSEL_];
    __shared__ int rows_s[NSEL_];
    __shared__ float g1_s[32];
    __shared__ float pw_s[32][CB_];                  // g2-scaled window probs
    const int h = blockIdx.y;
    const int q0 = blockIdx.x * 32;
    const int tid = threadIdx.x, lane = tid & 63, wave = tid >> 6;
    const size_t kvbase = (size_t)h * L_ * D_;

    for (int i = tid; i < 32 * D_; i += 256) {
        int qq = i / D_, d = i - qq * D_;
        q_s[qq][d] = q32[((size_t)h * L_ + q0 + qq) * D_ + d];
    }
    if (tid < NSEL_) {
        int t = tid / CB_;
        rows_s[tid] = idxp[h * TOPK_ + t] * CB_ + (tid - t * CB_);
    }
    __syncthreads();

    for (int i = tid; i < 119 * D_; i += 256) {
        int key = i / D_, d = i - key * D_;
        int row = (key < NSEL_) ? rows_s[key] : (L_ - CB_ + (key - NSEL_));
        ks_s[key][d] = k16[kvbase + (size_t)row * D_ + d];
        vsT[d][key]  = v32[kvbase + (size_t)row * D_ + d];
    }
    __syncthreads();

    if (tid < 32) {   // gates + window softmax (x g2)
        float a0 = bg[0], a1 = bg[1], a2 = bg[2];
        for (int d = 0; d < D_; d++) {
            float qd = q_s[tid][d];
            a0 += qd * wg[d * 3 + 0];
            a1 += qd * wg[d * 3 + 1];
            a2 += qd * wg[d * 3 + 2];
        }
        float gm = fmaxf(a0, fmaxf(a1, a2));
        float e0 = __expf(a0 - gm), e1 = __expf(a1 - gm), e2 = __expf(a2 - gm);
        float ginv = 1.f / (e0 + e1 + e2);
        g1_s[tid] = e1 * ginv;
        float g2 = e2 * ginv;
        float sw[CB_];
        float m = -1e30f;
        for (int i = 0; i < CB_; i++) {
            float ss = 0.f;
            for (int d = 0; d < D_; d++) ss += q_s[tid][d] * b2f(ks_s[NSEL_ + i][d]);
            sw[i] = ss * SCALE;
            m = fmaxf(m, sw[i]);
        }
        float lsum = 0.f;
        for (int i = 0; i < CB_; i++) { sw[i] = __expf(sw[i] - m); lsum += sw[i]; }
        float winv = g2 / lsum;
        for (int i = 0; i < CB_; i++) pw_s[tid][i] = sw[i] * winv;
    }
    __syncthreads();

    const bool v1 = (64 + lane) < NSEL_;
    const int row1c = v1 ? (64 + lane) : 0;
    for (int g = 0; g < 2; g++) {
        const int qb2 = wave * 8 + g * 4;
        float s0[4] = {0, 0, 0, 0}, s1[4] = {0, 0, 0, 0};
        for (int dc = 0; dc < 10; dc++) {
            float4 qv[4];
#pragma unroll
            for (int qi = 0; qi < 4; qi++) qv[qi] = *(const float4*)&q_s[qb2 + qi][dc * 4];
            uint2 ra = *(const uint2*)&ks_s[lane][dc * 4];
            uint2 rb = *(const uint2*)&ks_s[row1c][dc * 4];
            float a0, a1, a2, a3, c0, c1, c2, c3;
            b2x2(ra.x, a0, a1); b2x2(ra.y, a2, a3);
            b2x2(rb.x, c0, c1); b2x2(rb.y, c2, c3);
#pragma unroll
            for (int qi = 0; qi < 4; qi++) {
                s0[qi] += qv[qi].x * a0 + qv[qi].y * a1 + qv[qi].z * a2 + qv[qi].w * a3;
                s1[qi] += qv[qi].x * c0 + qv[qi].y * c1 + qv[qi].z * c2 + qv[qi].w * c3;
            }
        }
        {
            float ka = b2f(ks_s[lane][40]);
            float kb = b2f(ks_s[row1c][40]);
#pragma unroll
            for (int qi = 0; qi < 4; qi++) {
                float qt = q_s[qb2 + qi][40];
                s0[qi] += qt * ka; s1[qi] += qt * kb;
            }
        }
#pragma unroll
        for (int qi = 0; qi < 4; qi++) {
            float a0 = s0[qi] * SCALE;
            float a1 = v1 ? s1[qi] * SCALE : -1e30f;
            float m = fmaxf(a0, a1);
            for (int o = 32; o; o >>= 1) m = fmaxf(m, __shfl_xor(m, o));
            float e0 = __expf(a0 - m);
            float e1 = v1 ? __expf(a1 - m) : 0.f;
            float lsum = e0 + e1;
            for (int o = 32; o; o >>= 1) lsum += __shfl_xor(lsum, o);
            float inv = 1.f / lsum;
            p_s[qb2 + qi][lane] = f2b(e0 * inv);
            if (v1) p_s[qb2 + qi][64 + lane] = f2b(e1 * inv);
        }
    }
    __syncthreads();

    if (lane < D_) {
        for (int g = 0; g < 2; g++) {
            const int qb2 = wave * 8 + g * 4;
            float acc[4] = {0, 0, 0, 0};
            for (int jc = 0; jc < NSEL_; jc += 4) {
                float2 va = *(const float2*)&vsT[lane][jc];
                float2 vb = *(const float2*)&vsT[lane][jc + 2];
#pragma unroll
                for (int qi = 0; qi < 4; qi++) {
                    uint2 pp = *(const uint2*)&p_s[qb2 + qi][jc];
                    float p0, p1, p2, p3;
                    b2x2(pp.x, p0, p1); b2x2(pp.y, p2, p3);
                    acc[qi] += p0 * va.x + p1 * va.y + p2 * vb.x + p3 * vb.y;
                }
            }
#pragma unroll
            for (int qi = 0; qi < 4; qi++) {
                int row = qb2 + qi;
                float wvv = 0.f;
#pragma unroll
                for (int i = 0; i < CB_; i++) wvv += pw_s[row][i] * vsT[lane][NSEL_ + i];
                float* op = &outp[((size_t)(b * L_ + q0 + row)) * (H_ * D_) + h * D_ + lane];
                *op = *op + g1_s[row] * acc[qi] + wvv;
            }
        }
    }
}

extern "C" void kernel_launch(void* const* d_in, const int* in_sizes, int n_in,
                              void* d_out, int out_size, void* d_ws, size_t ws_size,
                              hipStream_t stream) {
    (void)in_sizes; (void)n_in;
    const float* x  = (const float*)d_in[0];
    const float* wq = (const float*)d_in[1];  const float* bq = (const float*)d_in[2];
    const float* wk = (const float*)d_in[3];  const float* bk = (const float*)d_in[4];
    const float* wv = (const float*)d_in[5];  const float* bv = (const float*)d_in[6];
    const float* w1 = (const float*)d_in[7];  const float* b1 = (const float*)d_in[8];
    const float* w2 = (const float*)d_in[9];  const float* b2 = (const float*)d_in[10];
    const float* wg = (const float*)d_in[11]; const float* bg = (const float*)d_in[12];

    if (d_ws == nullptr || ws_size < WS_NEEDED) {
        k_fail<<<dim3((out_size + 255) / 256), 256, 0, stream>>>((float*)d_out, out_size);
        return;
    }

    char* ws = (char*)d_ws;
    float*  r1   = (float*)(ws + OFF_R1);    // k32 then q32
    float*  v32  = (float*)(ws + OFF_V32);
    bfu*    k16  = (bfu*)(ws + OFF_K16);
    float*  kc   = (float*)(ws + OFF_KC);
    bfu*    vc16 = (bfu*)(ws + OFF_VC16);
    double* bsc  = (double*)(ws + OFF_BS);
    int*    idxp = (int*)(ws + OFF_IDX);
    float*  outp = (float*)d_out;
    // atomic-free block-score partials if workspace allows (else replicated fp64 atomics)
    const bool big = (ws_size >= WS_BIG);
    float*  bsp  = big ? (float*)(ws + OFF_BSP) : (float*)nullptr;

    for (int b = 0; b < B_; b++) {
        if (!big)
            k_zero_d<<<dim3((NREP_ * H_ * LC_ + 255) / 256), 256, 0, stream>>>(bsc, NREP_ * H_ * LC_);
        // K -> r1 and V -> v32 in one fused launch
        k_proj2<<<dim3(L_ / 16, 2, 2), 256, 0, stream>>>(x, wk, bk, r1, wv, bv, v32, b);
        k_cmlp<<<dim3(H_ * LC_ / 4), 256, 0, stream>>>(r1, w1, b1, w2, b2, kc, k16, (bfu*)nullptr);
        // Q -> r1 (overwrites k32; cmlpK done)
        k_proj2<<<dim3(L_ / 16, 2, 1), 256, 0, stream>>>(x, wq, bq, r1, wq, bq, r1, b);
        k_cmlp<<<dim3(H_ * LC_ / 4), 256, 0, stream>>>(v32, w1, b1, w2, b2, (float*)nullptr, (bfu*)nullptr, vc16);
        k_comp<<<dim3(QB_, H_), 256, 0, stream>>>(r1, kc, vc16, wg, bg, outp, bsc, bsp, b);
        k_topk<<<dim3(H_), 64, 0, stream>>>(bsc, bsp, idxp);
        k_selwin<<<dim3(QB_, H_), 256, 0, stream>>>(r1, k16, v32, idxp, wg, bg, outp, b);
    }
}